// Round 3
// baseline (57015.930 us; speedup 1.0000x reference)
//
#include <hip/hip_runtime.h>
#include <math.h>

#define STEPS 19
#define NEG_SLOPE 0.01f
#define THREADS 256
#define R 4                       // rows per thread: one LDS weight read feeds R*4 FMAs
#define ROWS_PER_BLOCK (THREADS * R)

__device__ __forceinline__ float lrelu(float x) {
    return fmaxf(x, NEG_SLOPE * x);    // slope<1 => max(x, 0.01x)
}

__device__ __forceinline__ float sigm(float x) {
    return __builtin_amdgcn_rcpf(1.0f + __expf(-x));
}

__global__ __launch_bounds__(THREADS, 2) void recurrent_kernel(
    const float* __restrict__ w,
    const float* __restrict__ Wh1, const float* __restrict__ bh1,
    const float* __restrict__ Wh2, const float* __restrict__ bh2,
    const float* __restrict__ Wh3, const float* __restrict__ bh3,
    const float* __restrict__ Wz1, const float* __restrict__ bz1,
    const float* __restrict__ Wz2, const float* __restrict__ bz2,
    const float* __restrict__ Wz3, const float* __restrict__ bz3,
    float* __restrict__ out, int nrows)
{
    // Layer-1 packed {W[0][k], W[1][k], b[k], 0} -> one ds_read_b128 per k.
    __shared__ float4 sH1[50];
    __shared__ float4 sZ1[50];
    // W2 as float4 chunks: row k = chunks [5k .. 5k+4]  -> 5x ds_read_b128 per k.
    __shared__ float4 sWh2v[250];
    __shared__ float4 sWz2v[250];
    __shared__ float  sbh2[20]; __shared__ float sbz2[20];
    __shared__ float2 sWh3[20]; __shared__ float2 sWz3[20];
    __shared__ float2 sbh3v;    __shared__ float2 sbz3v;

    const int t = threadIdx.x;
    if (t < 50) {
        sH1[t] = make_float4(Wh1[t], Wh1[50 + t], bh1[t], 0.0f);
        sZ1[t] = make_float4(Wz1[t], Wz1[50 + t], bz1[t], 0.0f);
    }
    if (t < 250) {
        sWh2v[t] = ((const float4*)Wh2)[t];
        sWz2v[t] = ((const float4*)Wz2)[t];
    }
    if (t < 20) {
        sbh2[t] = bh2[t];
        sbz2[t] = bz2[t];
        sWh3[t] = make_float2(Wh3[2 * t], Wh3[2 * t + 1]);
        sWz3[t] = make_float2(Wz3[2 * t], Wz3[2 * t + 1]);
    }
    if (t == 0) {
        sbh3v = make_float2(bh3[0], bh3[1]);
        sbz3v = make_float2(bz3[0], bz3[1]);
    }
    __syncthreads();

    // Thread t in block b owns rows  b*ROWS_PER_BLOCK + t + j*THREADS,  j=0..R-1
    const int base = blockIdx.x * ROWS_PER_BLOCK + t;

    float h0[R], h1[R];
    bool valid[R];
    #pragma unroll
    for (int j = 0; j < R; ++j) {
        const int row = base + j * THREADS;
        valid[j] = row < nrows;
        if (valid[j]) {
            const float2 w2 = *(const float2*)(w + 2 * (size_t)row);
            h0[j] = w2.x; h1[j] = w2.y;
        } else { h0[j] = 0.0f; h1[j] = 0.0f; }
    }

    for (int s = 0; s < STEPS; ++s) {
        float acc[R][20];

        // ---- h path: fused [2]->[50]->[20], no [50] array ----
        #pragma unroll
        for (int i = 0; i < 20; ++i) {
            const float b = sbh2[i];
            #pragma unroll
            for (int j = 0; j < R; ++j) acc[j][i] = b;
        }
        #pragma unroll
        for (int k = 0; k < 50; ++k) {
            const float4 wk = sH1[k];
            float a[R];
            #pragma unroll
            for (int j = 0; j < R; ++j)
                a[j] = lrelu(fmaf(h1[j], wk.y, fmaf(h0[j], wk.x, wk.z)));
            #pragma unroll
            for (int q = 0; q < 5; ++q) {
                const float4 wq = sWh2v[k * 5 + q];   // 1 LDS read -> 4R FMAs
                #pragma unroll
                for (int j = 0; j < R; ++j) {
                    acc[j][4 * q + 0] = fmaf(a[j], wq.x, acc[j][4 * q + 0]);
                    acc[j][4 * q + 1] = fmaf(a[j], wq.y, acc[j][4 * q + 1]);
                    acc[j][4 * q + 2] = fmaf(a[j], wq.z, acc[j][4 * q + 2]);
                    acc[j][4 * q + 3] = fmaf(a[j], wq.w, acc[j][4 * q + 3]);
                }
            }
        }
        // layer h3: [20] -> [2]
        float nh0[R], nh1[R];
        #pragma unroll
        for (int j = 0; j < R; ++j) { nh0[j] = sbh3v.x; nh1[j] = sbh3v.y; }
        #pragma unroll
        for (int i = 0; i < 20; ++i) {
            const float2 w3 = sWh3[i];                // shared across the R rows
            #pragma unroll
            for (int j = 0; j < R; ++j) {
                const float a = lrelu(acc[j][i]);
                nh0[j] = fmaf(a, w3.x, nh0[j]);
                nh1[j] = fmaf(a, w3.y, nh1[j]);
            }
        }
        #pragma unroll
        for (int j = 0; j < R; ++j) { h0[j] = lrelu(nh0[j]); h1[j] = lrelu(nh1[j]); }

        // ---- z path (uses the NEW h) ----
        #pragma unroll
        for (int i = 0; i < 20; ++i) {
            const float b = sbz2[i];
            #pragma unroll
            for (int j = 0; j < R; ++j) acc[j][i] = b;
        }
        #pragma unroll
        for (int k = 0; k < 50; ++k) {
            const float4 wk = sZ1[k];
            float zk[R];
            #pragma unroll
            for (int j = 0; j < R; ++j)
                zk[j] = sigm(fmaf(h1[j], wk.y, fmaf(h0[j], wk.x, wk.z)));
            #pragma unroll
            for (int q = 0; q < 5; ++q) {
                const float4 wq = sWz2v[k * 5 + q];
                #pragma unroll
                for (int j = 0; j < R; ++j) {
                    acc[j][4 * q + 0] = fmaf(zk[j], wq.x, acc[j][4 * q + 0]);
                    acc[j][4 * q + 1] = fmaf(zk[j], wq.y, acc[j][4 * q + 1]);
                    acc[j][4 * q + 2] = fmaf(zk[j], wq.z, acc[j][4 * q + 2]);
                    acc[j][4 * q + 3] = fmaf(zk[j], wq.w, acc[j][4 * q + 3]);
                }
            }
        }
        float zo0[R], zo1[R];
        #pragma unroll
        for (int j = 0; j < R; ++j) { zo0[j] = sbz3v.x; zo1[j] = sbz3v.y; }
        #pragma unroll
        for (int i = 0; i < 20; ++i) {
            const float2 w3 = sWz3[i];
            #pragma unroll
            for (int j = 0; j < R; ++j) {
                const float zz = sigm(acc[j][i]);
                zo0[j] = fmaf(zz, w3.x, zo0[j]);
                zo1[j] = fmaf(zz, w3.y, zo1[j]);
            }
        }
        #pragma unroll
        for (int j = 0; j < R; ++j) {
            if (valid[j]) {
                float2 o; o.x = sigm(zo0[j]); o.y = sigm(zo1[j]);
                const int row = base + j * THREADS;
                *(float2*)(out + (size_t)row * (STEPS * 2) + 2 * s) = o;
            }
        }
    }
}

extern "C" void kernel_launch(void* const* d_in, const int* in_sizes, int n_in,
                              void* d_out, int out_size, void* d_ws, size_t ws_size,
                              hipStream_t stream) {
    const float* w   = (const float*)d_in[0];
    const float* Wh1 = (const float*)d_in[1];
    const float* bh1 = (const float*)d_in[2];
    const float* Wh2 = (const float*)d_in[3];
    const float* bh2 = (const float*)d_in[4];
    const float* Wh3 = (const float*)d_in[5];
    const float* bh3 = (const float*)d_in[6];
    const float* Wz1 = (const float*)d_in[7];
    const float* bz1 = (const float*)d_in[8];
    const float* Wz2 = (const float*)d_in[9];
    const float* bz2 = (const float*)d_in[10];
    const float* Wz3 = (const float*)d_in[11];
    const float* bz3 = (const float*)d_in[12];
    float* out = (float*)d_out;

    const int nrows = in_sizes[0] / 2;  // w is [B,2]
    const int blocks = (nrows + ROWS_PER_BLOCK - 1) / ROWS_PER_BLOCK;

    recurrent_kernel<<<blocks, THREADS, 0, stream>>>(
        w, Wh1, bh1, Wh2, bh2, Wh3, bh3,
        Wz1, bz1, Wz2, bz2, Wz3, bz3, out, nrows);
}